// Round 11
// baseline (304.210 us; speedup 1.0000x reference)
//
#include <hip/hip_runtime.h>

// LSAGEDirected: 3 directed mean-agg hops (concat in/out) + linear projection.
// R10: gather2+GEMM fused (h2 never hits global), memset folded into prep,
//      bucket_scan folded into csr_build. 6 dispatches total.
// N=50000 nodes, E=800000 edges: 64 ->128 ->[fused gather+MFMA]-> 256 --agg--> 128.
#define NN 50000
#define NE 800000
#define NBUCK 100
#define BUCK_N 500        // NN / NBUCK
#define CAP 10016         // per-bucket pair capacity (avg 8000)
#define CAPS 9024         // LDS sort buffer capacity (avg 8000, ~11 sigma)
#define PA_BLOCKS 500
#define PA_CHUNK 1600     // NE / PA_BLOCKS

typedef __attribute__((ext_vector_type(8))) short short8;
typedef __attribute__((ext_vector_type(4))) float floatx4;

// ---- bf16 helpers (ushort storage; RNE convert, shift-based upconvert) ----
__device__ __forceinline__ unsigned short f2b(float x) {
    unsigned u = __float_as_uint(x);
    return (unsigned short)((u + 0x7fffu + ((u >> 16) & 1u)) >> 16);
}
__device__ __forceinline__ unsigned pk2(float lo, float hi) {
    return (unsigned)f2b(lo) | ((unsigned)f2b(hi) << 16);
}
__device__ __forceinline__ float blo(unsigned u) { return __uint_as_float(u << 16); }
__device__ __forceinline__ float bhi(unsigned u) { return __uint_as_float(u & 0xffff0000u); }
__device__ __forceinline__ void acc8(uint4 u, float* a) {
    a[0] += blo(u.x); a[1] += bhi(u.x);
    a[2] += blo(u.y); a[3] += bhi(u.y);
    a[4] += blo(u.z); a[5] += bhi(u.z);
    a[6] += blo(u.w); a[7] += bhi(u.w);
}

// ---------- fused prep: featb (0..3124) + B fold (3125..3380) + gcnt zero (3381) ----------
__global__ void prep_kernel(const float4* __restrict__ f32, uint2* __restrict__ fb,
                            const float* __restrict__ W, unsigned short* __restrict__ Bnk,
                            int* __restrict__ gcnt) {
    int bid = blockIdx.x;
    if (bid < 3125) {          // featb: NN*16 float4 -> uint2
        int idx = bid * 256 + threadIdx.x;
        float4 v = f32[idx];
        fb[idx] = make_uint2(pk2(v.x, v.y), pk2(v.z, v.w));
    } else if (bid < 3381) {   // Bnk bf16 [n][k] 256x256
        int idx = (bid - 3125) * 256 + threadIdx.x;   // 65536
        int n = idx >> 8, k = idx & 255;
        float v = (n < 128) ? W[n * 512 + k] : W[(n - 128) * 512 + 256 + k];
        Bnk[idx] = f2b(v);
    } else {                   // zero gcnt_in(128) + gcnt_out(128), contiguous
        gcnt[threadIdx.x] = 0;
    }
}

// ---------- Phase A: bucket edges by owner (dst for in-dir, src for out-dir) ----------
__global__ __launch_bounds__(256) void bucket_kernel(const int* __restrict__ src,
                                                     const int* __restrict__ dst,
                                                     int* __restrict__ gcnt_in,
                                                     int* __restrict__ gcnt_out,
                                                     int2* __restrict__ pin,
                                                     int2* __restrict__ pout) {
    __shared__ int cin[NBUCK], cout[NBUCK], rin[NBUCK], rout[NBUCK];
    int tid = threadIdx.x;
    if (tid < NBUCK) { cin[tid] = 0; cout[tid] = 0; }
    __syncthreads();
    int e0 = blockIdx.x * PA_CHUNK, e1 = e0 + PA_CHUNK;
    for (int e = e0 + tid; e < e1; e += 256) {
        atomicAdd(&cin[dst[e] / BUCK_N], 1);
        atomicAdd(&cout[src[e] / BUCK_N], 1);
    }
    __syncthreads();
    if (tid < NBUCK) {
        rin[tid]  = atomicAdd(&gcnt_in[tid], cin[tid]);
        rout[tid] = atomicAdd(&gcnt_out[tid], cout[tid]);
        cin[tid] = 0; cout[tid] = 0;
    }
    __syncthreads();
    for (int e = e0 + tid; e < e1; e += 256) {
        int s = src[e], d = dst[e];
        int bi = d / BUCK_N;
        int p = atomicAdd(&cin[bi], 1);
        pin[(size_t)bi * CAP + rin[bi] + p] = make_int2(d, s);   // (owner, neighbor)
        int bo = s / BUCK_N;
        int q = atomicAdd(&cout[bo], 1);
        pout[(size_t)bo * CAP + rout[bo] + q] = make_int2(s, d); // (owner, neighbor)
    }
}

// ---------- Phase B: per-(bucket,dir) CSR; neighbor-bucket-ordered lists ----------
// Base offsets computed locally from gcnt (bucket_scan folded in).
__global__ __launch_bounds__(1024) void csr_build_kernel(const int2* __restrict__ pin,
                                                         const int2* __restrict__ pout,
                                                         const int* __restrict__ gcnt_in,
                                                         const int* __restrict__ gcnt_out,
                                                         int* __restrict__ row_in,
                                                         int* __restrict__ row_out,
                                                         int* __restrict__ csr_in,
                                                         int* __restrict__ csr_out) {
    bool dirout = blockIdx.x >= NBUCK;
    int b = dirout ? blockIdx.x - NBUCK : blockIdx.x;
    const int2* pairs = (dirout ? pout : pin) + (size_t)b * CAP;
    const int* gcnt = dirout ? gcnt_out : gcnt_in;
    int cnt = gcnt[b];
    int base = 0;
    for (int i = 0; i < b; ++i) base += gcnt[i];   // <=99 L2-hit loads, uniform
    int* row = dirout ? row_out : row_in;
    int* csr = dirout ? csr_out : csr_in;
    int lo = b * BUCK_N;
    __shared__ unsigned sbuf[CAPS];                // 36 KB
    __shared__ int deg[BUCK_N], incl[BUCK_N], cur[BUCK_N];
    __shared__ int hnb[NBUCK], snb[NBUCK], cnb[NBUCK];
    int tid = threadIdx.x;
    if (tid < BUCK_N) { deg[tid] = 0; cur[tid] = 0; }
    if (tid < NBUCK) { hnb[tid] = 0; cnb[tid] = 0; }
    __syncthreads();
    for (int i = tid; i < cnt; i += 1024) {
        int2 pr = pairs[i];
        atomicAdd(&deg[pr.x - lo], 1);
        atomicAdd(&hnb[pr.y / BUCK_N], 1);
    }
    __syncthreads();
    if (tid < BUCK_N) incl[tid] = deg[tid];
    if (tid < NBUCK) snb[tid] = hnb[tid];
    __syncthreads();
    for (int off = 1; off < BUCK_N; off <<= 1) {
        int v = 0, w = 0;
        if (tid < BUCK_N && tid >= off) v = incl[tid - off];
        if (tid < NBUCK && tid >= off) w = snb[tid - off];
        __syncthreads();
        if (tid < BUCK_N) incl[tid] += v;
        if (tid < NBUCK && off < NBUCK) snb[tid] += w;
        __syncthreads();
    }
    if (tid < BUCK_N) row[lo + tid] = base + incl[tid] - deg[tid];
    if (tid == 0 && b == NBUCK - 1) row[NN] = base + incl[BUCK_N - 1];
    __syncthreads();
    if (cnt <= CAPS) {
        for (int i = tid; i < cnt; i += 1024) {
            int2 pr = pairs[i];
            int nb = pr.y / BUCK_N;
            int pos = snb[nb] - hnb[nb] + atomicAdd(&cnb[nb], 1);
            sbuf[pos] = ((unsigned)(pr.x - lo) << 17) | (unsigned)pr.y;
        }
        __syncthreads();
        for (int i = tid; i < cnt; i += 1024) {
            unsigned k = sbuf[i];
            int li = k >> 17;
            int pos = atomicAdd(&cur[li], 1);
            csr[base + incl[li] - deg[li] + pos] = (int)(k & 0x1FFFFu);
        }
    } else {   // overflow fallback: unsorted (correct, just less locality)
        for (int i = tid; i < cnt; i += 1024) {
            int2 pr = pairs[i];
            int li = pr.x - lo;
            int pos = atomicAdd(&cur[li], 1);
            csr[base + incl[li] - deg[li] + pos] = pr.y;
        }
    }
}

// ---------- hop 1: featb bf16 [NN][64] -> h1 bf16 [NN][128]; 16 thr/node, unroll 4 ----------
__global__ void gather1_kernel(const uint4* __restrict__ feat,
                               const int* __restrict__ row_in, const int* __restrict__ csr_in,
                               const int* __restrict__ row_out, const int* __restrict__ csr_out,
                               uint4* __restrict__ h1) {
    unsigned idx = blockIdx.x * 256 + threadIdx.x;   // NN*16 exactly
    unsigned n = idx >> 4, r = idx & 15;             // r: 0-7 in-dir, 8-15 out-dir
    bool is_out = (r >= 8);
    unsigned f = r & 7;
    const int* row = is_out ? row_out : row_in;
    const int* csr = is_out ? csr_out : csr_in;
    int beg = row[n], end = row[n + 1];
    float inv = 1.0f / fmaxf((float)(end - beg), 1.0f);
    float a[8] = {};
    int j = beg;
    for (; j + 3 < end; j += 4) {
        uint4 u0 = feat[(size_t)csr[j] * 8 + f];
        uint4 u1 = feat[(size_t)csr[j + 1] * 8 + f];
        uint4 u2 = feat[(size_t)csr[j + 2] * 8 + f];
        uint4 u3 = feat[(size_t)csr[j + 3] * 8 + f];
        acc8(u0, a); acc8(u1, a); acc8(u2, a); acc8(u3, a);
    }
    for (; j < end; ++j) acc8(feat[(size_t)csr[j] * 8 + f], a);
    uint4 o;
    o.x = pk2(a[0] * inv, a[1] * inv);
    o.y = pk2(a[2] * inv, a[3] * inv);
    o.z = pk2(a[4] * inv, a[5] * inv);
    o.w = pk2(a[6] * inv, a[7] * inv);
    h1[(size_t)n * 16 + r] = o;
}

// ---------- fused hop2 + MFMA GEMM: g[NN][256] = gather(h1) @ Bnk^T, h2 in LDS ----------
// Block 256 thr: gathers 64-node h2-tile into LDS, then per-wave 16x256 MFMA.
__global__ __launch_bounds__(256) void g2gemm_kernel(const uint4* __restrict__ h1,
                                                     const int* __restrict__ row_in,
                                                     const int* __restrict__ csr_in,
                                                     const int* __restrict__ row_out,
                                                     const int* __restrict__ csr_out,
                                                     const unsigned short* __restrict__ Bnk,
                                                     unsigned short* __restrict__ g) {
    __shared__ unsigned short pool[64 * 264];        // h2 tile, later reused as C staging
    __shared__ unsigned short Bs[16][264];
    int tid = threadIdx.x;
    int wave = tid >> 6, lane = tid & 63;
    int l15 = lane & 15, q = lane >> 4;
    int m0 = blockIdx.x * 64;

    // ---- gather prologue: 8 groups of 8 nodes; thread = (node, r) like gather2 ----
    {
        int r = tid & 31;
        bool is_out = (r >= 16);
        unsigned f = r & 15;
        const int* row = is_out ? row_out : row_in;
        const int* csr = is_out ? csr_out : csr_in;
        for (int grp = 0; grp < 8; ++grp) {
            int ln = grp * 8 + (tid >> 5);
            int n = m0 + ln;
            uint4 o = make_uint4(0u, 0u, 0u, 0u);
            if (n < NN) {
                int beg = row[n], end = row[n + 1];
                float inv = 1.0f / fmaxf((float)(end - beg), 1.0f);
                float a[8] = {};
                int j = beg;
                for (; j + 3 < end; j += 4) {
                    uint4 u0 = h1[(size_t)csr[j] * 16 + f];
                    uint4 u1 = h1[(size_t)csr[j + 1] * 16 + f];
                    uint4 u2 = h1[(size_t)csr[j + 2] * 16 + f];
                    uint4 u3 = h1[(size_t)csr[j + 3] * 16 + f];
                    acc8(u0, a); acc8(u1, a); acc8(u2, a); acc8(u3, a);
                }
                for (; j < end; ++j) acc8(h1[(size_t)csr[j] * 16 + f], a);
                o.x = pk2(a[0] * inv, a[1] * inv);
                o.y = pk2(a[2] * inv, a[3] * inv);
                o.z = pk2(a[4] * inv, a[5] * inv);
                o.w = pk2(a[6] * inv, a[7] * inv);
            }
            *(uint4*)&pool[ln * 264 + r * 8] = o;
        }
    }
    __syncthreads();

    // ---- A-frags from LDS (each wave reads only its own 16 rows) ----
    short8 af[8];
#pragma unroll
    for (int s = 0; s < 8; ++s)
        af[s] = *(const short8*)&pool[(wave * 16 + l15) * 264 + s * 32 + q * 8];
    floatx4 acc[16];
#pragma unroll
    for (int c = 0; c < 16; ++c) acc[c] = (floatx4){0.f, 0.f, 0.f, 0.f};
#pragma unroll
    for (int c = 0; c < 16; ++c) {
        {   // stage B rows 16c..16c+16 (512B each)
            int nl = tid >> 4, seg = tid & 15;
            const uint4* srcp = (const uint4*)(Bnk + ((size_t)(16 * c + nl)) * 256 + seg * 16);
            uint4 v0 = srcp[0], v1 = srcp[1];
            *(uint4*)&Bs[nl][seg * 16] = v0;
            *(uint4*)&Bs[nl][seg * 16 + 8] = v1;
        }
        __syncthreads();
#pragma unroll
        for (int s = 0; s < 8; ++s) {
            short8 bf = *(const short8*)&Bs[l15][s * 32 + q * 8];
            acc[c] = __builtin_amdgcn_mfma_f32_16x16x32_bf16(af[s], bf, acc[c], 0, 0, 0);
        }
        __syncthreads();
    }
    // ---- epilogue: reuse pool as per-wave C strips; coalesced bf16 stores ----
    unsigned short* Cw = pool + wave * 16 * 264;
#pragma unroll
    for (int c = 0; c < 16; ++c)
#pragma unroll
        for (int rr = 0; rr < 4; ++rr)
            Cw[(q * 4 + rr) * 264 + 16 * c + l15] = f2b(acc[c][rr]);
    __syncthreads();
#pragma unroll
    for (int i = 0; i < 8; ++i) {
        int t = i * 64 + lane;
        int rrow = t >> 5;
        int seg = t & 31;
        int m = m0 + wave * 16 + rrow;
        if (m < NN) {
            uint4 v = *(const uint4*)&Cw[rrow * 264 + seg * 8];
            *(uint4*)(g + (size_t)m * 256 + seg * 8) = v;
        }
    }
}

// ---------- final hop + bias: gather g bf16, both directions; 16 thr/node, unroll 4 ----------
__global__ void final_kernel(const uint4* __restrict__ g,
                             const int* __restrict__ row_in, const int* __restrict__ csr_in,
                             const int* __restrict__ row_out, const int* __restrict__ csr_out,
                             const float4* __restrict__ b4, float4* __restrict__ out) {
    unsigned idx = blockIdx.x * 256 + threadIdx.x;   // NN*16 exactly
    unsigned n = idx >> 4, f = idx & 15;
    float a[8] = {};
    {
        int beg = row_in[n], end = row_in[n + 1];
        float inv = 1.0f / fmaxf((float)(end - beg), 1.0f);
        float s[8] = {};
        int j = beg;
        for (; j + 3 < end; j += 4) {
            uint4 u0 = g[(size_t)csr_in[j] * 32 + f];
            uint4 u1 = g[(size_t)csr_in[j + 1] * 32 + f];
            uint4 u2 = g[(size_t)csr_in[j + 2] * 32 + f];
            uint4 u3 = g[(size_t)csr_in[j + 3] * 32 + f];
            acc8(u0, s); acc8(u1, s); acc8(u2, s); acc8(u3, s);
        }
        for (; j < end; ++j) acc8(g[(size_t)csr_in[j] * 32 + f], s);
#pragma unroll
        for (int i = 0; i < 8; ++i) a[i] += s[i] * inv;
    }
    {
        int beg = row_out[n], end = row_out[n + 1];
        float inv = 1.0f / fmaxf((float)(end - beg), 1.0f);
        float s[8] = {};
        int j = beg;
        for (; j + 3 < end; j += 4) {
            uint4 u0 = g[(size_t)csr_out[j] * 32 + 16 + f];
            uint4 u1 = g[(size_t)csr_out[j + 1] * 32 + 16 + f];
            uint4 u2 = g[(size_t)csr_out[j + 2] * 32 + 16 + f];
            uint4 u3 = g[(size_t)csr_out[j + 3] * 32 + 16 + f];
            acc8(u0, s); acc8(u1, s); acc8(u2, s); acc8(u3, s);
        }
        for (; j < end; ++j) acc8(g[(size_t)csr_out[j] * 32 + 16 + f], s);
#pragma unroll
        for (int i = 0; i < 8; ++i) a[i] += s[i] * inv;
    }
    float4 b0 = b4[2 * f], b1 = b4[2 * f + 1];
    out[(size_t)n * 32 + 2 * f]     = make_float4(a[0] + b0.x, a[1] + b0.y, a[2] + b0.z, a[3] + b0.w);
    out[(size_t)n * 32 + 2 * f + 1] = make_float4(a[4] + b1.x, a[5] + b1.y, a[6] + b1.z, a[7] + b1.w);
}

extern "C" void kernel_launch(void* const* d_in, const int* in_sizes, int n_in,
                              void* d_out, int out_size, void* d_ws, size_t ws_size,
                              hipStream_t stream) {
    const float* feature = (const float*)d_in[0];
    const int*   edges   = (const int*)d_in[1];   // [2, NE]: src row then dst row
    const float* W       = (const float*)d_in[2];
    const float* b       = (const float*)d_in[3];
    const int* src = edges;
    const int* dst = edges + NE;
    float* out = (float*)d_out;

    // Workspace layout (16B-aligned chunks first). ~68 MB total.
    unsigned short* featb = (unsigned short*)d_ws;       // NN*64 bf16
    unsigned short* h1b = featb + (size_t)NN * 64;       // NN*128 bf16
    unsigned short* gb  = h1b + (size_t)NN * 128;        // NN*256 bf16
    unsigned short* Bnk = gb + (size_t)NN * 256;         // 65536 bf16
    int2* pin  = (int2*)(Bnk + 65536);                   // NBUCK*CAP pairs
    int2* pout = pin + (size_t)NBUCK * CAP;              // NBUCK*CAP pairs
    int* csr_in  = (int*)(pout + (size_t)NBUCK * CAP);   // NE
    int* csr_out = csr_in + NE;                          // NE
    int* row_in  = csr_out + NE;                         // NN+1
    int* row_out = row_in + NN + 1;                      // NN+1
    int* gcnt_in  = row_out + NN + 1;                    // 128 (zeroed by prep)
    int* gcnt_out = gcnt_in + 128;                       // 128 (contiguous with gcnt_in)

    prep_kernel<<<3382, 256, 0, stream>>>((const float4*)feature, (uint2*)featb, W, Bnk, gcnt_in);
    bucket_kernel<<<PA_BLOCKS, 256, 0, stream>>>(src, dst, gcnt_in, gcnt_out, pin, pout);
    csr_build_kernel<<<2 * NBUCK, 1024, 0, stream>>>(pin, pout, gcnt_in, gcnt_out,
                                                     row_in, row_out, csr_in, csr_out);
    // hop 1: featb(64 bf16) -> h1(128 bf16)
    gather1_kernel<<<(NN * 16) / 256, 256, 0, stream>>>(
        (const uint4*)featb, row_in, csr_in, row_out, csr_out, (uint4*)h1b);
    // fused hop 2 + projection: g = gather(h1) @ Bnk^T (h2 stays in LDS)
    g2gemm_kernel<<<(NN + 63) / 64, 256, 0, stream>>>(
        (const uint4*)h1b, row_in, csr_in, row_out, csr_out, Bnk, gb);
    // hop 3 + bias: aggregate g rows -> out (fp32)
    final_kernel<<<(NN * 16) / 256, 256, 0, stream>>>(
        (const uint4*)gb, row_in, csr_in, row_out, csr_out, (const float4*)b, (float4*)out);
}

// Round 12
// 258.814 us; speedup vs baseline: 1.1754x; 1.1754x over previous
//
#include <hip/hip_runtime.h>

// LSAGEDirected: 3 directed mean-agg hops (concat in/out) + linear projection.
// R11: revert R10 fusion (g2gemm 118us @ 18% occ vs 70us split — TLP collapse).
//      Best-known: R8 split kernels + R9 nbr-sorted CSR + R10 dispatch folding.
// N=50000 nodes, E=800000 edges: 64 ->128 ->256 --MFMA--> 256 --agg--> 128.
#define NN 50000
#define NE 800000
#define NBUCK 100
#define BUCK_N 500        // NN / NBUCK
#define CAP 10016         // per-bucket pair capacity (avg 8000)
#define CAPS 9024         // LDS sort buffer capacity (avg 8000, ~11 sigma)
#define PA_BLOCKS 500
#define PA_CHUNK 1600     // NE / PA_BLOCKS

typedef __attribute__((ext_vector_type(8))) short short8;
typedef __attribute__((ext_vector_type(4))) float floatx4;

// ---- bf16 helpers (ushort storage; RNE convert, shift-based upconvert) ----
__device__ __forceinline__ unsigned short f2b(float x) {
    unsigned u = __float_as_uint(x);
    return (unsigned short)((u + 0x7fffu + ((u >> 16) & 1u)) >> 16);
}
__device__ __forceinline__ unsigned pk2(float lo, float hi) {
    return (unsigned)f2b(lo) | ((unsigned)f2b(hi) << 16);
}
__device__ __forceinline__ float blo(unsigned u) { return __uint_as_float(u << 16); }
__device__ __forceinline__ float bhi(unsigned u) { return __uint_as_float(u & 0xffff0000u); }
__device__ __forceinline__ void acc8(uint4 u, float* a) {
    a[0] += blo(u.x); a[1] += bhi(u.x);
    a[2] += blo(u.y); a[3] += bhi(u.y);
    a[4] += blo(u.z); a[5] += bhi(u.z);
    a[6] += blo(u.w); a[7] += bhi(u.w);
}

// ---------- fused prep: featb (0..3124) + B fold (3125..3380) + gcnt zero (3381) ----------
__global__ void prep_kernel(const float4* __restrict__ f32, uint2* __restrict__ fb,
                            const float* __restrict__ W, unsigned short* __restrict__ Bnk,
                            int* __restrict__ gcnt) {
    int bid = blockIdx.x;
    if (bid < 3125) {          // featb: NN*16 float4 -> uint2
        int idx = bid * 256 + threadIdx.x;
        float4 v = f32[idx];
        fb[idx] = make_uint2(pk2(v.x, v.y), pk2(v.z, v.w));
    } else if (bid < 3381) {   // Bnk bf16 [n][k] 256x256
        int idx = (bid - 3125) * 256 + threadIdx.x;   // 65536
        int n = idx >> 8, k = idx & 255;
        float v = (n < 128) ? W[n * 512 + k] : W[(n - 128) * 512 + 256 + k];
        Bnk[idx] = f2b(v);
    } else {                   // zero gcnt_in(128) + gcnt_out(128), contiguous
        gcnt[threadIdx.x] = 0;
    }
}

// ---------- Phase A: bucket edges by owner (dst for in-dir, src for out-dir) ----------
__global__ __launch_bounds__(256) void bucket_kernel(const int* __restrict__ src,
                                                     const int* __restrict__ dst,
                                                     int* __restrict__ gcnt_in,
                                                     int* __restrict__ gcnt_out,
                                                     int2* __restrict__ pin,
                                                     int2* __restrict__ pout) {
    __shared__ int cin[NBUCK], cout[NBUCK], rin[NBUCK], rout[NBUCK];
    int tid = threadIdx.x;
    if (tid < NBUCK) { cin[tid] = 0; cout[tid] = 0; }
    __syncthreads();
    int e0 = blockIdx.x * PA_CHUNK, e1 = e0 + PA_CHUNK;
    for (int e = e0 + tid; e < e1; e += 256) {
        atomicAdd(&cin[dst[e] / BUCK_N], 1);
        atomicAdd(&cout[src[e] / BUCK_N], 1);
    }
    __syncthreads();
    if (tid < NBUCK) {
        rin[tid]  = atomicAdd(&gcnt_in[tid], cin[tid]);
        rout[tid] = atomicAdd(&gcnt_out[tid], cout[tid]);
        cin[tid] = 0; cout[tid] = 0;
    }
    __syncthreads();
    for (int e = e0 + tid; e < e1; e += 256) {
        int s = src[e], d = dst[e];
        int bi = d / BUCK_N;
        int p = atomicAdd(&cin[bi], 1);
        pin[(size_t)bi * CAP + rin[bi] + p] = make_int2(d, s);   // (owner, neighbor)
        int bo = s / BUCK_N;
        int q = atomicAdd(&cout[bo], 1);
        pout[(size_t)bo * CAP + rout[bo] + q] = make_int2(s, d); // (owner, neighbor)
    }
}

// ---------- Phase B: per-(bucket,dir) CSR; neighbor-bucket-ordered lists ----------
// Base offsets computed locally from gcnt (scan folded in).
__global__ __launch_bounds__(1024) void csr_build_kernel(const int2* __restrict__ pin,
                                                         const int2* __restrict__ pout,
                                                         const int* __restrict__ gcnt_in,
                                                         const int* __restrict__ gcnt_out,
                                                         int* __restrict__ row_in,
                                                         int* __restrict__ row_out,
                                                         int* __restrict__ csr_in,
                                                         int* __restrict__ csr_out) {
    bool dirout = blockIdx.x >= NBUCK;
    int b = dirout ? blockIdx.x - NBUCK : blockIdx.x;
    const int2* pairs = (dirout ? pout : pin) + (size_t)b * CAP;
    const int* gcnt = dirout ? gcnt_out : gcnt_in;
    int cnt = gcnt[b];
    int base = 0;
    for (int i = 0; i < b; ++i) base += gcnt[i];   // <=99 L2-hit loads, uniform
    int* row = dirout ? row_out : row_in;
    int* csr = dirout ? csr_out : csr_in;
    int lo = b * BUCK_N;
    __shared__ unsigned sbuf[CAPS];                // 36 KB
    __shared__ int deg[BUCK_N], incl[BUCK_N], cur[BUCK_N];
    __shared__ int hnb[NBUCK], snb[NBUCK], cnb[NBUCK];
    int tid = threadIdx.x;
    if (tid < BUCK_N) { deg[tid] = 0; cur[tid] = 0; }
    if (tid < NBUCK) { hnb[tid] = 0; cnb[tid] = 0; }
    __syncthreads();
    for (int i = tid; i < cnt; i += 1024) {
        int2 pr = pairs[i];
        atomicAdd(&deg[pr.x - lo], 1);
        atomicAdd(&hnb[pr.y / BUCK_N], 1);
    }
    __syncthreads();
    if (tid < BUCK_N) incl[tid] = deg[tid];
    if (tid < NBUCK) snb[tid] = hnb[tid];
    __syncthreads();
    for (int off = 1; off < BUCK_N; off <<= 1) {
        int v = 0, w = 0;
        if (tid < BUCK_N && tid >= off) v = incl[tid - off];
        if (tid < NBUCK && tid >= off) w = snb[tid - off];
        __syncthreads();
        if (tid < BUCK_N) incl[tid] += v;
        if (tid < NBUCK && off < NBUCK) snb[tid] += w;
        __syncthreads();
    }
    if (tid < BUCK_N) row[lo + tid] = base + incl[tid] - deg[tid];
    if (tid == 0 && b == NBUCK - 1) row[NN] = base + incl[BUCK_N - 1];
    __syncthreads();
    if (cnt <= CAPS) {
        for (int i = tid; i < cnt; i += 1024) {
            int2 pr = pairs[i];
            int nb = pr.y / BUCK_N;
            int pos = snb[nb] - hnb[nb] + atomicAdd(&cnb[nb], 1);
            sbuf[pos] = ((unsigned)(pr.x - lo) << 17) | (unsigned)pr.y;
        }
        __syncthreads();
        for (int i = tid; i < cnt; i += 1024) {
            unsigned k = sbuf[i];
            int li = k >> 17;
            int pos = atomicAdd(&cur[li], 1);
            csr[base + incl[li] - deg[li] + pos] = (int)(k & 0x1FFFFu);
        }
    } else {   // overflow fallback: unsorted (correct, just less locality)
        for (int i = tid; i < cnt; i += 1024) {
            int2 pr = pairs[i];
            int li = pr.x - lo;
            int pos = atomicAdd(&cur[li], 1);
            csr[base + incl[li] - deg[li] + pos] = pr.y;
        }
    }
}

// ---------- hop 1: featb bf16 [NN][64] -> h1 bf16 [NN][128]; 16 thr/node, unroll 4 ----------
__global__ void gather1_kernel(const uint4* __restrict__ feat,
                               const int* __restrict__ row_in, const int* __restrict__ csr_in,
                               const int* __restrict__ row_out, const int* __restrict__ csr_out,
                               uint4* __restrict__ h1) {
    unsigned idx = blockIdx.x * 256 + threadIdx.x;   // NN*16 exactly
    unsigned n = idx >> 4, r = idx & 15;             // r: 0-7 in-dir, 8-15 out-dir
    bool is_out = (r >= 8);
    unsigned f = r & 7;
    const int* row = is_out ? row_out : row_in;
    const int* csr = is_out ? csr_out : csr_in;
    int beg = row[n], end = row[n + 1];
    float inv = 1.0f / fmaxf((float)(end - beg), 1.0f);
    float a[8] = {};
    int j = beg;
    for (; j + 3 < end; j += 4) {
        uint4 u0 = feat[(size_t)csr[j] * 8 + f];
        uint4 u1 = feat[(size_t)csr[j + 1] * 8 + f];
        uint4 u2 = feat[(size_t)csr[j + 2] * 8 + f];
        uint4 u3 = feat[(size_t)csr[j + 3] * 8 + f];
        acc8(u0, a); acc8(u1, a); acc8(u2, a); acc8(u3, a);
    }
    for (; j < end; ++j) acc8(feat[(size_t)csr[j] * 8 + f], a);
    uint4 o;
    o.x = pk2(a[0] * inv, a[1] * inv);
    o.y = pk2(a[2] * inv, a[3] * inv);
    o.z = pk2(a[4] * inv, a[5] * inv);
    o.w = pk2(a[6] * inv, a[7] * inv);
    h1[(size_t)n * 16 + r] = o;
}

// ---------- hop 2: h1 bf16 [NN][128] -> h2 bf16 [NN][256]; 32 thr/node, unroll 4 ----------
__global__ void gather2_kernel(const uint4* __restrict__ h1,
                               const int* __restrict__ row_in, const int* __restrict__ csr_in,
                               const int* __restrict__ row_out, const int* __restrict__ csr_out,
                               uint4* __restrict__ h2) {
    unsigned idx = blockIdx.x * 256 + threadIdx.x;   // NN*32 exactly
    unsigned n = idx >> 5, r = idx & 31;
    bool is_out = (r >= 16);
    unsigned f = r & 15;                             // uint4 slot within 16-slot h1 row
    const int* row = is_out ? row_out : row_in;
    const int* csr = is_out ? csr_out : csr_in;
    int beg = row[n], end = row[n + 1];
    float inv = 1.0f / fmaxf((float)(end - beg), 1.0f);
    float a[8] = {};
    int j = beg;
    for (; j + 3 < end; j += 4) {
        uint4 u0 = h1[(size_t)csr[j] * 16 + f];
        uint4 u1 = h1[(size_t)csr[j + 1] * 16 + f];
        uint4 u2 = h1[(size_t)csr[j + 2] * 16 + f];
        uint4 u3 = h1[(size_t)csr[j + 3] * 16 + f];
        acc8(u0, a); acc8(u1, a); acc8(u2, a); acc8(u3, a);
    }
    for (; j < end; ++j) acc8(h1[(size_t)csr[j] * 16 + f], a);
    uint4 o;
    o.x = pk2(a[0] * inv, a[1] * inv);
    o.y = pk2(a[2] * inv, a[3] * inv);
    o.z = pk2(a[4] * inv, a[5] * inv);
    o.w = pk2(a[6] * inv, a[7] * inv);
    h2[(size_t)n * 32 + r] = o;
}

// ---------- MFMA GEMM: g[NN][256] bf16 = h2[NN][256] bf16 @ Bnk^T ----------
// 128 rows/block (2 m-tiles per wave): halves B restaging + barriers per output.
__global__ __launch_bounds__(256) void gemm_mfma_kernel(const unsigned short* __restrict__ A,
                                                        const unsigned short* __restrict__ Bnk,
                                                        unsigned short* __restrict__ C) {
    __shared__ unsigned short Bs[16][264];
    __shared__ unsigned short Cb[4][16][264];
    int tid = threadIdx.x;
    int wave = tid >> 6, lane = tid & 63;
    int l15 = lane & 15, q = lane >> 4;
    int m0 = blockIdx.x * 128;
    short8 af[2][8];
#pragma unroll
    for (int t = 0; t < 2; ++t) {
        int mrow = m0 + (wave + 4 * t) * 16 + l15;
        const unsigned short* Arow = A + (size_t)min(mrow, NN - 1) * 256;
#pragma unroll
        for (int s = 0; s < 8; ++s)
            af[t][s] = *(const short8*)(Arow + s * 32 + q * 8);
    }
    floatx4 acc[2][16];
#pragma unroll
    for (int t = 0; t < 2; ++t)
#pragma unroll
        for (int c = 0; c < 16; ++c) acc[t][c] = (floatx4){0.f, 0.f, 0.f, 0.f};
#pragma unroll
    for (int c = 0; c < 16; ++c) {
        {   // stage B rows 16c..16c+16 (512B each)
            int nl = tid >> 4, seg = tid & 15;
            const uint4* srcp = (const uint4*)(Bnk + ((size_t)(16 * c + nl)) * 256 + seg * 16);
            uint4 v0 = srcp[0], v1 = srcp[1];
            *(uint4*)&Bs[nl][seg * 16] = v0;
            *(uint4*)&Bs[nl][seg * 16 + 8] = v1;
        }
        __syncthreads();
#pragma unroll
        for (int s = 0; s < 8; ++s) {
            short8 bf = *(const short8*)&Bs[l15][s * 32 + q * 8];
            acc[0][c] = __builtin_amdgcn_mfma_f32_16x16x32_bf16(af[0][s], bf, acc[0][c], 0, 0, 0);
            acc[1][c] = __builtin_amdgcn_mfma_f32_16x16x32_bf16(af[1][s], bf, acc[1][c], 0, 0, 0);
        }
        __syncthreads();
    }
#pragma unroll
    for (int t = 0; t < 2; ++t) {
#pragma unroll
        for (int c = 0; c < 16; ++c)
#pragma unroll
            for (int r = 0; r < 4; ++r)
                Cb[wave][q * 4 + r][16 * c + l15] = f2b(acc[t][c][r]);
        __syncthreads();
#pragma unroll
        for (int i = 0; i < 8; ++i) {
            int tt = i * 64 + lane;
            int rrow = tt >> 5;
            int seg = tt & 31;
            int m = m0 + (wave + 4 * t) * 16 + rrow;
            if (m < NN) {
                uint4 v = *(const uint4*)&Cb[wave][rrow][seg * 8];
                *(uint4*)(C + (size_t)m * 256 + seg * 8) = v;
            }
        }
        __syncthreads();
    }
}

// ---------- final hop + bias: gather g bf16, both directions; 16 thr/node, unroll 4 ----------
__global__ void final_kernel(const uint4* __restrict__ g,
                             const int* __restrict__ row_in, const int* __restrict__ csr_in,
                             const int* __restrict__ row_out, const int* __restrict__ csr_out,
                             const float4* __restrict__ b4, float4* __restrict__ out) {
    unsigned idx = blockIdx.x * 256 + threadIdx.x;   // NN*16 exactly
    unsigned n = idx >> 4, f = idx & 15;
    float a[8] = {};
    {
        int beg = row_in[n], end = row_in[n + 1];
        float inv = 1.0f / fmaxf((float)(end - beg), 1.0f);
        float s[8] = {};
        int j = beg;
        for (; j + 3 < end; j += 4) {
            uint4 u0 = g[(size_t)csr_in[j] * 32 + f];
            uint4 u1 = g[(size_t)csr_in[j + 1] * 32 + f];
            uint4 u2 = g[(size_t)csr_in[j + 2] * 32 + f];
            uint4 u3 = g[(size_t)csr_in[j + 3] * 32 + f];
            acc8(u0, s); acc8(u1, s); acc8(u2, s); acc8(u3, s);
        }
        for (; j < end; ++j) acc8(g[(size_t)csr_in[j] * 32 + f], s);
#pragma unroll
        for (int i = 0; i < 8; ++i) a[i] += s[i] * inv;
    }
    {
        int beg = row_out[n], end = row_out[n + 1];
        float inv = 1.0f / fmaxf((float)(end - beg), 1.0f);
        float s[8] = {};
        int j = beg;
        for (; j + 3 < end; j += 4) {
            uint4 u0 = g[(size_t)csr_out[j] * 32 + 16 + f];
            uint4 u1 = g[(size_t)csr_out[j + 1] * 32 + 16 + f];
            uint4 u2 = g[(size_t)csr_out[j + 2] * 32 + 16 + f];
            uint4 u3 = g[(size_t)csr_out[j + 3] * 32 + 16 + f];
            acc8(u0, s); acc8(u1, s); acc8(u2, s); acc8(u3, s);
        }
        for (; j < end; ++j) acc8(g[(size_t)csr_out[j] * 32 + 16 + f], s);
#pragma unroll
        for (int i = 0; i < 8; ++i) a[i] += s[i] * inv;
    }
    float4 b0 = b4[2 * f], b1 = b4[2 * f + 1];
    out[(size_t)n * 32 + 2 * f]     = make_float4(a[0] + b0.x, a[1] + b0.y, a[2] + b0.z, a[3] + b0.w);
    out[(size_t)n * 32 + 2 * f + 1] = make_float4(a[4] + b1.x, a[5] + b1.y, a[6] + b1.z, a[7] + b1.w);
}

extern "C" void kernel_launch(void* const* d_in, const int* in_sizes, int n_in,
                              void* d_out, int out_size, void* d_ws, size_t ws_size,
                              hipStream_t stream) {
    const float* feature = (const float*)d_in[0];
    const int*   edges   = (const int*)d_in[1];   // [2, NE]: src row then dst row
    const float* W       = (const float*)d_in[2];
    const float* b       = (const float*)d_in[3];
    const int* src = edges;
    const int* dst = edges + NE;
    float* out = (float*)d_out;

    // Workspace layout (16B-aligned chunks first). ~94 MB total.
    unsigned short* featb = (unsigned short*)d_ws;       // NN*64 bf16
    unsigned short* h1b = featb + (size_t)NN * 64;       // NN*128 bf16
    unsigned short* h2b = h1b + (size_t)NN * 128;        // NN*256 bf16
    unsigned short* gb  = h2b + (size_t)NN * 256;        // NN*256 bf16
    unsigned short* Bnk = gb + (size_t)NN * 256;         // 65536 bf16
    int2* pin  = (int2*)(Bnk + 65536);                   // NBUCK*CAP pairs
    int2* pout = pin + (size_t)NBUCK * CAP;              // NBUCK*CAP pairs
    int* csr_in  = (int*)(pout + (size_t)NBUCK * CAP);   // NE
    int* csr_out = csr_in + NE;                          // NE
    int* row_in  = csr_out + NE;                         // NN+1
    int* row_out = row_in + NN + 1;                      // NN+1
    int* gcnt_in  = row_out + NN + 1;                    // 128 (zeroed by prep)
    int* gcnt_out = gcnt_in + 128;                       // 128 (contiguous with gcnt_in)

    prep_kernel<<<3382, 256, 0, stream>>>((const float4*)feature, (uint2*)featb, W, Bnk, gcnt_in);
    bucket_kernel<<<PA_BLOCKS, 256, 0, stream>>>(src, dst, gcnt_in, gcnt_out, pin, pout);
    csr_build_kernel<<<2 * NBUCK, 1024, 0, stream>>>(pin, pout, gcnt_in, gcnt_out,
                                                     row_in, row_out, csr_in, csr_out);
    // hop 1: featb(64 bf16) -> h1(128 bf16)
    gather1_kernel<<<(NN * 16) / 256, 256, 0, stream>>>(
        (const uint4*)featb, row_in, csr_in, row_out, csr_out, (uint4*)h1b);
    // hop 2: h1(128 bf16) -> h2(256 bf16)
    gather2_kernel<<<(NN * 32) / 256, 256, 0, stream>>>(
        (const uint4*)h1b, row_in, csr_in, row_out, csr_out, (uint4*)h2b);
    // projection (folded before hop 3): g = h2 @ Bnk^T via bf16 MFMA, 128 rows/block
    gemm_mfma_kernel<<<(NN + 127) / 128, 256, 0, stream>>>(h2b, Bnk, gb);
    // hop 3 + bias: aggregate g rows -> out (fp32)
    final_kernel<<<(NN * 16) / 256, 256, 0, stream>>>(
        (const uint4*)gb, row_in, csr_in, row_out, csr_out, (const float4*)b, (float4*)out);
}